// Round 6
// baseline (259.178 us; speedup 1.0000x reference)
//
#include <hip/hip_runtime.h>
#include <hip/hip_bf16.h>

typedef unsigned short u16;
typedef unsigned int u32;
typedef __bf16 bf16x8 __attribute__((ext_vector_type(8)));
typedef float float4_ __attribute__((ext_vector_type(4)));

#define B_ 2
#define S_ 2048
#define E_ 1024
#define H_ 16
#define DH_ 64
#define M_ (B_*S_)
#define SCALE_ 0.03125f
#define LOG2E_ 1.4426950408889634f

__device__ __forceinline__ u16 f2bf(float f) {
    unsigned int x = __float_as_uint(f);
    x += 0x7fffu + ((x >> 16) & 1u);   // RNE
    return (u16)(x >> 16);
}

template <typename T> struct raw8;
template <> struct raw8<float> { float4_ lo, hi; };
template <> struct raw8<u16>   { bf16x8 v; };

__device__ __forceinline__ raw8<float> ldr8(const float* p) {
    raw8<float> r; const float4_* q = (const float4_*)p; r.lo = q[0]; r.hi = q[1]; return r;
}
__device__ __forceinline__ raw8<u16> ldr8(const u16* p) {
    raw8<u16> r; r.v = *(const bf16x8*)p; return r;
}
__device__ __forceinline__ bf16x8 cvt8(const raw8<u16>& r) { return r.v; }
__device__ __forceinline__ bf16x8 cvt8(const raw8<float>& r) {
    union { bf16x8 v; __hip_bfloat162 h[4]; } u;
    u.h[0] = __float22bfloat162_rn(float2{r.lo[0], r.lo[1]});
    u.h[1] = __float22bfloat162_rn(float2{r.lo[2], r.lo[3]});
    u.h[2] = __float22bfloat162_rn(float2{r.hi[0], r.hi[1]});
    u.h[3] = __float22bfloat162_rn(float2{r.hi[2], r.hi[3]});
    return u.v;
}
__device__ __forceinline__ bf16x8 ld8(const u16* p) { return *(const bf16x8*)p; }

// async 16B global -> LDS. LDS dest must be wave-uniform base + lane*16.
__device__ __forceinline__ void async16(u16* lds, const u16* g) {
    __builtin_amdgcn_global_load_lds(
        (const __attribute__((address_space(1))) u32*)g,
        (__attribute__((address_space(3))) u32*)lds, 16, 0, 0);
}

// ---- weight f32 -> bf16 conversion pass ----
__global__ __launch_bounds__(256)
void convw_kernel(const float* __restrict__ Wq, const float* __restrict__ Wk,
                  const float* __restrict__ Wv, const float* __restrict__ Wo,
                  u16* __restrict__ Wqb, u16* __restrict__ Wkb,
                  u16* __restrict__ Wvb, u16* __restrict__ Wob) {
    const int which = blockIdx.y;
    const float* src = which == 0 ? Wq : which == 1 ? Wk : which == 2 ? Wv : Wo;
    u16* dst        = which == 0 ? Wqb : which == 1 ? Wkb : which == 2 ? Wvb : Wob;
    size_t off = ((size_t)blockIdx.x * 256 + threadIdx.x) * 8;
    *(bf16x8*)&dst[off] = cvt8(ldr8(&src[off]));
}

// ---- projections: C = cscale * A(f32)[M,1024] * Wb(bf16)[1024,1024]^T ----
// 128x128 tile, BK=32, single-barrier double-buffer with COMPILE-TIME buffer
// indices (manual unroll x2). Per step: issue async W(k+1)->Ws[NXT] first;
// frag-read buf[CUR]; store A(k+1) regs->As[NXT]; load A(k+2) regs; 16 MFMA;
// barrier (drain covered by the whole step). grid (32=bm, 8=bn, 3=z).
__global__ __launch_bounds__(256)
void proj_kernel(const float* __restrict__ q, const float* __restrict__ k, const float* __restrict__ v,
                 const u16* __restrict__ Wqb, const u16* __restrict__ Wkb, const u16* __restrict__ Wvb,
                 u16* __restrict__ Qh, u16* __restrict__ Kh, u16* __restrict__ Vt) {
    const int z = blockIdx.z;
    const float* A = (z == 0) ? q : (z == 1) ? k : v;
    const u16* Wb  = (z == 0) ? Wqb : (z == 1) ? Wkb : Wvb;
    u16* C         = (z == 0) ? Qh : (z == 1) ? Kh : Vt;
    const float cscale = (z == 0) ? SCALE_ : 1.0f;
    const int transV = (z == 2);
    const int bm = blockIdx.x * 128, bn = blockIdx.y * 128;

    __shared__ u16 As[2][128 * 32];
    __shared__ u16 Ws[2][128 * 32];

    const int tid  = threadIdx.x;
    const int lane = tid & 63;
    const int w    = tid >> 6;
    const int wr   = (w >> 1) * 64, wc = (w & 1) * 64;
    const int m16  = lane & 15, quad = lane >> 4, q4 = quad * 4;
    const int row0 = tid >> 2, kc0 = (tid & 3) * 8, row1 = row0 + 64;
    const int c1   = tid + 256;

    const u16* wg0 = &Wb[(size_t)(bn + (tid >> 2)) * 1024 + (tid & 3) * 8];
    const u16* wg1 = &Wb[(size_t)(bn + (c1 >> 2)) * 1024 + (c1 & 3) * 8];
    const float* ag0 = &A[(size_t)(bm + row0) * 1024 + kc0];
    const float* ag1 = &A[(size_t)(bm + row1) * 1024 + kc0];

    float4_ acc[4][4];
#pragma unroll
    for (int i = 0; i < 4; i++)
#pragma unroll
        for (int j = 0; j < 4; j++) acc[i][j] = (float4_){0.f, 0.f, 0.f, 0.f};

    // preamble: W(0) async -> Ws[0]; A(0) -> As[0]; A(1) in regs
    async16((u16*)((char*)&Ws[0][0] + (size_t)tid * 16), wg0);
    async16((u16*)((char*)&Ws[0][0] + (size_t)c1 * 16),  wg1);
    raw8<float> pa0 = ldr8(ag0), pa1 = ldr8(ag1);
    *(bf16x8*)&As[0][row0 * 32 + kc0] = cvt8(pa0);
    *(bf16x8*)&As[0][row1 * 32 + kc0] = cvt8(pa1);
    pa0 = ldr8(ag0 + 32); pa1 = ldr8(ag1 + 32);
    __syncthreads();

#define PROJ_STEP(CUR, NXT, KOFF, HAVENXT, HAVENXT2)                                   \
    {                                                                                  \
        if (HAVENXT) {                                                                 \
            async16((u16*)((char*)&Ws[NXT][0] + (size_t)tid * 16), wg0 + kb + (KOFF) + 32); \
            async16((u16*)((char*)&Ws[NXT][0] + (size_t)c1  * 16), wg1 + kb + (KOFF) + 32); \
        }                                                                              \
        bf16x8 af[4], bfr[4];                                                          \
        _Pragma("unroll") for (int rt = 0; rt < 4; rt++)                               \
            af[rt] = *(const bf16x8*)&As[CUR][(wr + rt * 16 + m16) * 32 + quad * 8];   \
        _Pragma("unroll") for (int ct = 0; ct < 4; ct++)                               \
            bfr[ct] = *(const bf16x8*)&Ws[CUR][(wc + ct * 16 + m16) * 32 + quad * 8];  \
        if (HAVENXT) {                                                                 \
            *(bf16x8*)&As[NXT][row0 * 32 + kc0] = cvt8(pa0);                           \
            *(bf16x8*)&As[NXT][row1 * 32 + kc0] = cvt8(pa1);                           \
            if (HAVENXT2) {                                                            \
                pa0 = ldr8(ag0 + kb + (KOFF) + 64);                                    \
                pa1 = ldr8(ag1 + kb + (KOFF) + 64);                                    \
            }                                                                          \
        }                                                                              \
        _Pragma("unroll") for (int rt = 0; rt < 4; rt++)                               \
            _Pragma("unroll") for (int ct = 0; ct < 4; ct++)                           \
                acc[rt][ct] = __builtin_amdgcn_mfma_f32_16x16x32_bf16(af[rt], bfr[ct], acc[rt][ct], 0, 0, 0); \
        if (HAVENXT) __syncthreads();                                                  \
    }

#pragma unroll 1
    for (int kb = 0; kb < 1024; kb += 64) {
        PROJ_STEP(0, 1, 0,  true,            kb + 64 < 1024)
        PROJ_STEP(1, 0, 32, kb + 64 < 1024,  kb + 96 < 1024)
    }
#undef PROJ_STEP

#pragma unroll
    for (int rt = 0; rt < 4; rt++)
#pragma unroll
        for (int ct = 0; ct < 4; ct++)
#pragma unroll
            for (int r = 0; r < 4; r++) {
                int row = bm + wr + rt * 16 + q4 + r;
                int col = bn + wc + ct * 16 + m16;
                u16 val = f2bf(acc[rt][ct][r] * cscale);
                if (!transV) {
                    C[(size_t)row * 1024 + col] = val;
                } else {
                    int bb = row >> 11, s = row & 2047;
                    C[((size_t)(bb * 1024 + col)) * 2048 + s] = val;
                }
            }
}

// ---- output GEMM: C(f32) = AO(bf16)*Wob(bf16)^T, 128x64 tile, same pipeline ----
__global__ __launch_bounds__(256)
void out_kernel(const u16* __restrict__ AO, const u16* __restrict__ Wob, float* __restrict__ C) {
    const int bm = blockIdx.x * 128, bn = blockIdx.y * 64;

    __shared__ u16 As[2][128 * 32];
    __shared__ u16 Bs[2][64 * 32];

    const int tid  = threadIdx.x;
    const int lane = tid & 63;
    const int w    = tid >> 6;
    const int m16  = lane & 15, quad = lane >> 4, q4 = quad * 4;
    const int c1   = tid + 256;

    const u16* ag0 = &AO[(size_t)(bm + (tid >> 2)) * 1024 + (tid & 3) * 8];
    const u16* ag1 = &AO[(size_t)(bm + (c1 >> 2)) * 1024 + (c1 & 3) * 8];
    const u16* bg  = &Wob[(size_t)(bn + (tid >> 2)) * 1024 + (tid & 3) * 8];

    float4_ acc[2][4];
#pragma unroll
    for (int i = 0; i < 2; i++)
#pragma unroll
        for (int j = 0; j < 4; j++) acc[i][j] = (float4_){0.f, 0.f, 0.f, 0.f};

    async16((u16*)((char*)&As[0][0] + (size_t)tid * 16), ag0);
    async16((u16*)((char*)&As[0][0] + (size_t)c1 * 16),  ag1);
    async16((u16*)((char*)&Bs[0][0] + (size_t)tid * 16), bg);
    __syncthreads();

#define OUT_STEP(CUR, NXT, KOFF, HAVENXT)                                              \
    {                                                                                  \
        if (HAVENXT) {                                                                 \
            async16((u16*)((char*)&As[NXT][0] + (size_t)tid * 16), ag0 + kb + (KOFF) + 32); \
            async16((u16*)((char*)&As[NXT][0] + (size_t)c1  * 16), ag1 + kb + (KOFF) + 32); \
            async16((u16*)((char*)&Bs[NXT][0] + (size_t)tid * 16), bg  + kb + (KOFF) + 32); \
        }                                                                              \
        bf16x8 af[2], bfr[4];                                                          \
        _Pragma("unroll") for (int rt = 0; rt < 2; rt++)                               \
            af[rt] = *(const bf16x8*)&As[CUR][(w * 32 + rt * 16 + m16) * 32 + quad * 8]; \
        _Pragma("unroll") for (int ct = 0; ct < 4; ct++)                               \
            bfr[ct] = *(const bf16x8*)&Bs[CUR][(ct * 16 + m16) * 32 + quad * 8];       \
        _Pragma("unroll") for (int rt = 0; rt < 2; rt++)                               \
            _Pragma("unroll") for (int ct = 0; ct < 4; ct++)                           \
                acc[rt][ct] = __builtin_amdgcn_mfma_f32_16x16x32_bf16(af[rt], bfr[ct], acc[rt][ct], 0, 0, 0); \
        if (HAVENXT) __syncthreads();                                                  \
    }

#pragma unroll 1
    for (int kb = 0; kb < 1024; kb += 64) {
        OUT_STEP(0, 1, 0,  true)
        OUT_STEP(1, 0, 32, kb + 64 < 1024)
    }
#undef OUT_STEP

#pragma unroll
    for (int rt = 0; rt < 2; rt++)
#pragma unroll
        for (int ct = 0; ct < 4; ct++)
#pragma unroll
            for (int r = 0; r < 4; r++) {
                int row = bm + w * 32 + rt * 16 + q4 + r;
                int col = bn + ct * 16 + m16;
                C[(size_t)row * 1024 + col] = acc[rt][ct][r];
            }
}

// XOR swizzle for 64-col bf16 LDS tiles.
__device__ __forceinline__ int sw64(int row, int col) {
    return row * 64 + ((((col >> 3) ^ (row & 7)) << 3) | (col & 7));
}

// Flash attention, paired q-tiles, no max-reduction (scores bounded; exp2 safe),
// l as per-lane partials reduced at epilogue. 1 barrier per KV tile.
__global__ __launch_bounds__(256)
void attn_kernel(const u16* __restrict__ Qh, const u16* __restrict__ Kh,
                 const u16* __restrict__ Vt, u16* __restrict__ O) {
    const int h    = blockIdx.x;
    const int pair = blockIdx.y;
    const int tqA  = pair;
    const int tqB  = 31 - pair;
    const int b    = blockIdx.z;
    const int tid  = threadIdx.x;
    const int lane = tid & 63;
    const int w    = tid >> 6;
    const int m16  = lane & 15;
    const int quad = lane >> 4;
    const int q4   = quad * 4;

    __shared__ u16 Ks[2][64 * 64];
    __shared__ u16 Vs[2][64 * 64];
    __shared__ u16 PsA[64 * 64];
    __shared__ u16 PsB[64 * 64];

    const int srow0 = tid >> 3;
    const int skc0  = (tid & 7) * 8;
    const int sblk0 = ((skc0 >> 3) ^ (srow0 & 7)) << 3;
    const int srow1 = srow0 + 32;
    const int sblk1 = ((skc0 >> 3) ^ (srow1 & 7)) << 3;

    const size_t kbase = ((size_t)(b * S_)) * E_ + h * DH_;
    const size_t vbase = ((size_t)(b * 1024 + h * DH_)) * 2048;

    bf16x8 qfA[2], qfB[2];
    {
        const u16* qa = Qh + ((size_t)(b * S_ + tqA * 64 + w * 16 + m16)) * E_ + h * DH_;
        const u16* qb = Qh + ((size_t)(b * S_ + tqB * 64 + w * 16 + m16)) * E_ + h * DH_;
        qfA[0] = ld8(qa + quad * 8);  qfA[1] = ld8(qa + 32 + quad * 8);
        qfB[0] = ld8(qb + quad * 8);  qfB[1] = ld8(qb + 32 + quad * 8);
    }

    float lA[4] = {0.f, 0.f, 0.f, 0.f}, lB[4] = {0.f, 0.f, 0.f, 0.f};
    float4_ oA[4], oB[4];
#pragma unroll
    for (int dt = 0; dt < 4; dt++) { oA[dt] = (float4_){0.f,0.f,0.f,0.f}; oB[dt] = (float4_){0.f,0.f,0.f,0.f}; }

    *(bf16x8*)&Ks[0][srow0 * 64 + sblk0] = ld8(&Kh[kbase + (size_t)srow0 * E_ + skc0]);
    *(bf16x8*)&Ks[0][srow1 * 64 + sblk1] = ld8(&Kh[kbase + (size_t)srow1 * E_ + skc0]);
    *(bf16x8*)&Vs[0][srow0 * 64 + sblk0] = ld8(&Vt[vbase + (size_t)srow0 * 2048 + skc0]);
    *(bf16x8*)&Vs[0][srow1 * 64 + sblk1] = ld8(&Vt[vbase + (size_t)srow1 * 2048 + skc0]);
    __syncthreads();

    for (int t = 0; t <= tqB; t++) {
        const int cur = t & 1;

        bf16x8 kr0, kr1, vr0, vr1;
        const bool havepf = (t < tqB);
        if (havepf) {
            const size_t ko = kbase + (size_t)((t + 1) * 64) * E_;
            kr0 = ld8(&Kh[ko + (size_t)srow0 * E_ + skc0]);
            kr1 = ld8(&Kh[ko + (size_t)srow1 * E_ + skc0]);
            vr0 = ld8(&Vt[vbase + (size_t)srow0 * 2048 + (t + 1) * 64 + skc0]);
            vr1 = ld8(&Vt[vbase + (size_t)srow1 * 2048 + (t + 1) * 64 + skc0]);
        }

        auto process = [&](const bf16x8* qf, float* l_part, float4_* o_acc,
                           u16* Ps, int tqX) {
            const u16* Kc = &Ks[cur][0];
            const u16* Vc = &Vs[cur][0];
            float4_ sc[4];
#pragma unroll
            for (int ct = 0; ct < 4; ct++) sc[ct] = (float4_){0.f,0.f,0.f,0.f};
#pragma unroll
            for (int ks = 0; ks < 2; ks++)
#pragma unroll
                for (int ct = 0; ct < 4; ct++) {
                    bf16x8 kf = *(const bf16x8*)&Kc[sw64(ct * 16 + m16, ks * 32 + quad * 8)];
                    sc[ct] = __builtin_amdgcn_mfma_f32_16x16x32_bf16(qf[ks], kf, sc[ct], 0, 0, 0);
                }

            float p[4][4];
            if (t != tqX) {
#pragma unroll
                for (int ct = 0; ct < 4; ct++)
#pragma unroll
                    for (int r = 0; r < 4; r++) {
                        float pp = exp2f(sc[ct][r] * LOG2E_);
                        p[ct][r] = pp;
                        l_part[r] += pp;
                    }
            } else {
#pragma unroll
                for (int ct = 0; ct < 4; ct++)
#pragma unroll
                    for (int r = 0; r < 4; r++) {
                        int i_loc = w * 16 + q4 + r;
                        int j_loc = ct * 16 + m16;
                        bool allow = (j_loc < i_loc) || (tqX == 0 && i_loc == 0 && j_loc == 0);
                        float pp = allow ? exp2f(sc[ct][r] * LOG2E_) : 0.f;
                        p[ct][r] = pp;
                        l_part[r] += pp;
                    }
            }

#pragma unroll
            for (int ct = 0; ct < 4; ct++)
#pragma unroll
                for (int r = 0; r < 4; r++)
                    Ps[sw64(w * 16 + q4 + r, ct * 16 + m16)] = f2bf(p[ct][r]);

#pragma unroll
            for (int ks = 0; ks < 2; ks++) {
                bf16x8 pf = *(const bf16x8*)&Ps[sw64(w * 16 + m16, ks * 32 + quad * 8)];
#pragma unroll
                for (int dt = 0; dt < 4; dt++) {
                    bf16x8 vf = *(const bf16x8*)&Vc[sw64(dt * 16 + m16, ks * 32 + quad * 8)];
                    o_acc[dt] = __builtin_amdgcn_mfma_f32_16x16x32_bf16(pf, vf, o_acc[dt], 0, 0, 0);
                }
            }
        };

        process(qfB, lB, oB, PsB, tqB);
        if (t <= tqA) process(qfA, lA, oA, PsA, tqA);

        if (havepf) {
            const int nxt = cur ^ 1;
            *(bf16x8*)&Ks[nxt][srow0 * 64 + sblk0] = kr0;
            *(bf16x8*)&Ks[nxt][srow1 * 64 + sblk1] = kr1;
            *(bf16x8*)&Vs[nxt][srow0 * 64 + sblk0] = vr0;
            *(bf16x8*)&Vs[nxt][srow1 * 64 + sblk1] = vr1;
        }
        __syncthreads();
    }

    auto wrout = [&](const float4_* o_acc, const float* l_part, int tqX) {
        const size_t obase = ((size_t)(b * S_ + tqX * 64)) * E_ + h * DH_;
#pragma unroll
        for (int r = 0; r < 4; r++) {
            float l = l_part[r];
#pragma unroll
            for (int msk = 1; msk <= 8; msk <<= 1) l += __shfl_xor(l, msk);
            float inv_l = 1.0f / l;
            int row = w * 16 + q4 + r;
#pragma unroll
            for (int dt = 0; dt < 4; dt++) {
                int col = dt * 16 + m16;
                O[obase + (size_t)row * E_ + col] = f2bf(o_acc[dt][r] * inv_l);
            }
        }
    };
    wrout(oA, lA, tqA);
    wrout(oB, lB, tqB);
}

extern "C" void kernel_launch(void* const* d_in, const int* in_sizes, int n_in,
                              void* d_out, int out_size, void* d_ws, size_t ws_size,
                              hipStream_t stream) {
    const float* q  = (const float*)d_in[0];
    const float* k  = (const float*)d_in[1];
    const float* v  = (const float*)d_in[2];
    const float* Wq = (const float*)d_in[3];
    const float* Wk = (const float*)d_in[4];
    const float* Wv = (const float*)d_in[5];
    const float* Wo = (const float*)d_in[6];

    u16* ws  = (u16*)d_ws;
    u16* Qh  = ws;                          // [B*S,E] bf16, pre-scaled by SCALE_
    u16* Kh  = ws + (size_t)M_ * E_;
    u16* Vt  = ws + 2 * (size_t)M_ * E_;    // [B][1024][2048] bf16 V^T
    u16* AO  = ws + 3 * (size_t)M_ * E_;    // attn out; first 3*E*E aliased as W bufs
    u16* Wqb = AO;                          // dead before attn writes AO
    u16* Wkb = AO + (size_t)E_ * E_;
    u16* Wvb = AO + 2 * (size_t)E_ * E_;
    u16* Wob = ws + 4 * (size_t)M_ * E_;    // +2 MB

    dim3 blk(256);
    convw_kernel<<<dim3(512, 4), blk, 0, stream>>>(Wq, Wk, Wv, Wo, Wqb, Wkb, Wvb, Wob);
    proj_kernel<<<dim3(32, 8, 3), blk, 0, stream>>>(q, k, v, Wqb, Wkb, Wvb, Qh, Kh, Vt);
    attn_kernel<<<dim3(16, 16, 2), blk, 0, stream>>>(Qh, Kh, Vt, AO);
    out_kernel<<<dim3(32, 16), blk, 0, stream>>>(AO, Wob, (float*)d_out);
}

// Round 7
// 241.489 us; speedup vs baseline: 1.0733x; 1.0733x over previous
//
#include <hip/hip_runtime.h>
#include <hip/hip_bf16.h>

typedef unsigned short u16;
typedef unsigned int u32;
typedef __bf16 bf16x8 __attribute__((ext_vector_type(8)));
typedef float float4_ __attribute__((ext_vector_type(4)));

#define B_ 2
#define S_ 2048
#define E_ 1024
#define H_ 16
#define DH_ 64
#define M_ (B_*S_)
#define SCALE_ 0.03125f
#define LOG2E_ 1.4426950408889634f

__device__ __forceinline__ u16 f2bf(float f) {
    unsigned int x = __float_as_uint(f);
    x += 0x7fffu + ((x >> 16) & 1u);   // RNE
    return (u16)(x >> 16);
}

template <typename T> struct raw8;
template <> struct raw8<float> { float4_ lo, hi; };
template <> struct raw8<u16>   { bf16x8 v; };

__device__ __forceinline__ raw8<float> ldr8(const float* p) {
    raw8<float> r; const float4_* q = (const float4_*)p; r.lo = q[0]; r.hi = q[1]; return r;
}
__device__ __forceinline__ raw8<u16> ldr8(const u16* p) {
    raw8<u16> r; r.v = *(const bf16x8*)p; return r;
}
__device__ __forceinline__ bf16x8 cvt8(const raw8<u16>& r) { return r.v; }
__device__ __forceinline__ bf16x8 cvt8(const raw8<float>& r) {
    union { bf16x8 v; __hip_bfloat162 h[4]; } u;
    u.h[0] = __float22bfloat162_rn(float2{r.lo[0], r.lo[1]});
    u.h[1] = __float22bfloat162_rn(float2{r.lo[2], r.lo[3]});
    u.h[2] = __float22bfloat162_rn(float2{r.hi[0], r.hi[1]});
    u.h[3] = __float22bfloat162_rn(float2{r.hi[2], r.hi[3]});
    return u.v;
}
__device__ __forceinline__ bf16x8 ld8(const u16* p) { return *(const bf16x8*)p; }

// ---- weight f32 -> bf16 conversion pass ----
__global__ __launch_bounds__(256)
void convw_kernel(const float* __restrict__ Wq, const float* __restrict__ Wk,
                  const float* __restrict__ Wv, const float* __restrict__ Wo,
                  u16* __restrict__ Wqb, u16* __restrict__ Wkb,
                  u16* __restrict__ Wvb, u16* __restrict__ Wob) {
    const int which = blockIdx.y;
    const float* src = which == 0 ? Wq : which == 1 ? Wk : which == 2 ? Wv : Wo;
    u16* dst        = which == 0 ? Wqb : which == 1 ? Wkb : which == 2 ? Wvb : Wob;
    size_t off = ((size_t)blockIdx.x * 256 + threadIdx.x) * 8;
    *(bf16x8*)&dst[off] = cvt8(ldr8(&src[off]));
}

// BK=32 LDS tile: row*32 + swizzled 8-elem block. Block j at row r lives at
// j^( (r>>1)&3 ) — spreads the frag-read bank groups so ds_read_b128 is ~2-way.
__device__ __forceinline__ int ldsoff(int row, int j) {
    return row * 32 + ((j ^ ((row >> 1) & 3)) & 3) * 8;
}

// ---- projections: C = cscale * A(f32)[M,1024] * Wb(bf16)[1024,1024]^T ----
// 128x128 tile, BK=32, TWO-barrier single-buffer; BOTH operands register-
// prefetched across the MFMA block (loads for k+1 issued before MFMA of k,
// consumed after the next barrier — full-block latency cover; no async16).
// grid (32=bm, 8=bn, 3=z): XCD = bm%8 keeps an A-stripe per-XCD-L2-resident.
__global__ __launch_bounds__(256)
void proj_kernel(const float* __restrict__ q, const float* __restrict__ k, const float* __restrict__ v,
                 const u16* __restrict__ Wqb, const u16* __restrict__ Wkb, const u16* __restrict__ Wvb,
                 u16* __restrict__ Qh, u16* __restrict__ Kh, u16* __restrict__ Vt) {
    const int z = blockIdx.z;
    const float* A = (z == 0) ? q : (z == 1) ? k : v;
    const u16* Wb  = (z == 0) ? Wqb : (z == 1) ? Wkb : Wvb;
    u16* C         = (z == 0) ? Qh : (z == 1) ? Kh : Vt;
    const float cscale = (z == 0) ? SCALE_ : 1.0f;
    const int transV = (z == 2);
    const int bm = blockIdx.x * 128, bn = blockIdx.y * 128;

    __shared__ u16 As[128 * 32];
    __shared__ u16 Ws[128 * 32];

    const int tid  = threadIdx.x;
    const int lane = tid & 63;
    const int w    = tid >> 6;
    const int wr   = (w >> 1) * 64, wc = (w & 1) * 64;
    const int m16  = lane & 15, quad = lane >> 4, q4 = quad * 4;
    const int r0   = tid >> 2, j0 = tid & 3, kc0 = j0 * 8;   // staging: rows r0, r0+64
    const int st0  = ldsoff(r0, j0);                          // r0+64 has same swizzle
    const int sjf  = (m16 >> 1) & 3;                          // frag-read swizzle

    const float* ag0 = &A[(size_t)(bm + r0) * 1024 + kc0];
    const float* ag1 = &A[(size_t)(bm + r0 + 64) * 1024 + kc0];
    const u16*   wg0 = &Wb[(size_t)(bn + r0) * 1024 + kc0];
    const u16*   wg1 = &Wb[(size_t)(bn + r0 + 64) * 1024 + kc0];

    float4_ acc[4][4];
#pragma unroll
    for (int i = 0; i < 4; i++)
#pragma unroll
        for (int j = 0; j < 4; j++) acc[i][j] = (float4_){0.f, 0.f, 0.f, 0.f};

    raw8<float> pa0 = ldr8(ag0), pa1 = ldr8(ag1);
    bf16x8      pw0 = ld8(wg0),  pw1 = ld8(wg1);

    for (int k0 = 0; k0 < 1024; k0 += 32) {
        __syncthreads();                       // close prev iter's frag reads
        *(bf16x8*)&As[st0]           = cvt8(pa0);
        *(bf16x8*)&As[st0 + 64 * 32] = cvt8(pa1);
        *(bf16x8*)&Ws[st0]           = pw0;
        *(bf16x8*)&Ws[st0 + 64 * 32] = pw1;
        __syncthreads();                       // stores visible
        if (k0 + 32 < 1024) {                  // k+1 loads fly across the MFMA block
            pa0 = ldr8(ag0 + k0 + 32);
            pa1 = ldr8(ag1 + k0 + 32);
            pw0 = ld8(wg0 + k0 + 32);
            pw1 = ld8(wg1 + k0 + 32);
        }
        bf16x8 af[4], bfr[4];
#pragma unroll
        for (int rt = 0; rt < 4; rt++)
            af[rt] = *(const bf16x8*)&As[(wr + rt * 16 + m16) * 32 + ((quad ^ sjf) & 3) * 8];
#pragma unroll
        for (int ct = 0; ct < 4; ct++)
            bfr[ct] = *(const bf16x8*)&Ws[(wc + ct * 16 + m16) * 32 + ((quad ^ sjf) & 3) * 8];
#pragma unroll
        for (int rt = 0; rt < 4; rt++)
#pragma unroll
            for (int ct = 0; ct < 4; ct++)
                acc[rt][ct] = __builtin_amdgcn_mfma_f32_16x16x32_bf16(af[rt], bfr[ct], acc[rt][ct], 0, 0, 0);
    }

#pragma unroll
    for (int rt = 0; rt < 4; rt++)
#pragma unroll
        for (int ct = 0; ct < 4; ct++)
#pragma unroll
            for (int r = 0; r < 4; r++) {
                int row = bm + wr + rt * 16 + q4 + r;
                int col = bn + wc + ct * 16 + m16;
                u16 val = f2bf(acc[rt][ct][r] * cscale);
                if (!transV) {
                    C[(size_t)row * 1024 + col] = val;
                } else {
                    int bb = row >> 11, s = row & 2047;
                    C[((size_t)(bb * 1024 + col)) * 2048 + s] = val;
                }
            }
}

// ---- output GEMM: C(f32) = AO(bf16)*Wob(bf16)^T, 128x64 tile, same pipeline ----
__global__ __launch_bounds__(256)
void out_kernel(const u16* __restrict__ AO, const u16* __restrict__ Wob, float* __restrict__ C) {
    const int bm = blockIdx.x * 128, bn = blockIdx.y * 64;

    __shared__ u16 As[128 * 32];
    __shared__ u16 Bs[64 * 32];

    const int tid  = threadIdx.x;
    const int lane = tid & 63;
    const int w    = tid >> 6;
    const int m16  = lane & 15, quad = lane >> 4, q4 = quad * 4;
    const int r0   = tid >> 2, j0 = tid & 3, kc0 = j0 * 8;
    const int st0  = ldsoff(r0, j0);
    const int sjf  = (m16 >> 1) & 3;

    const u16* ag0 = &AO[(size_t)(bm + r0) * 1024 + kc0];
    const u16* ag1 = &AO[(size_t)(bm + r0 + 64) * 1024 + kc0];
    const u16* bg  = &Wob[(size_t)(bn + r0) * 1024 + kc0];   // r0<64 rows only used

    float4_ acc[2][4];
#pragma unroll
    for (int i = 0; i < 2; i++)
#pragma unroll
        for (int j = 0; j < 4; j++) acc[i][j] = (float4_){0.f, 0.f, 0.f, 0.f};

    bf16x8 pa0 = ld8(ag0), pa1 = ld8(ag1), pb = ld8(bg);

    for (int k0 = 0; k0 < 1024; k0 += 32) {
        __syncthreads();
        *(bf16x8*)&As[st0]           = pa0;
        *(bf16x8*)&As[st0 + 64 * 32] = pa1;
        if (r0 < 64) *(bf16x8*)&Bs[st0] = pb;
        __syncthreads();
        if (k0 + 32 < 1024) {
            pa0 = ld8(ag0 + k0 + 32);
            pa1 = ld8(ag1 + k0 + 32);
            pb  = ld8(bg  + k0 + 32);
        }
        bf16x8 af[2], bfr[4];
#pragma unroll
        for (int rt = 0; rt < 2; rt++)
            af[rt] = *(const bf16x8*)&As[(w * 32 + rt * 16 + m16) * 32 + ((quad ^ sjf) & 3) * 8];
#pragma unroll
        for (int ct = 0; ct < 4; ct++)
            bfr[ct] = *(const bf16x8*)&Bs[(ct * 16 + m16) * 32 + ((quad ^ sjf) & 3) * 8];
#pragma unroll
        for (int rt = 0; rt < 2; rt++)
#pragma unroll
            for (int ct = 0; ct < 4; ct++)
                acc[rt][ct] = __builtin_amdgcn_mfma_f32_16x16x32_bf16(af[rt], bfr[ct], acc[rt][ct], 0, 0, 0);
    }

#pragma unroll
    for (int rt = 0; rt < 2; rt++)
#pragma unroll
        for (int ct = 0; ct < 4; ct++)
#pragma unroll
            for (int r = 0; r < 4; r++) {
                int row = bm + w * 32 + rt * 16 + q4 + r;
                int col = bn + ct * 16 + m16;
                C[(size_t)row * 1024 + col] = acc[rt][ct][r];
            }
}

// XOR swizzle for 64-col bf16 LDS tiles.
__device__ __forceinline__ int sw64(int row, int col) {
    return row * 64 + ((((col >> 3) ^ (row & 7)) << 3) | (col & 7));
}

// Flash attention, paired q-tiles, no max-reduction (scores bounded; exp2 safe),
// l as per-lane partials reduced at epilogue. 1 barrier per KV tile. (R4 verbatim)
__global__ __launch_bounds__(256)
void attn_kernel(const u16* __restrict__ Qh, const u16* __restrict__ Kh,
                 const u16* __restrict__ Vt, u16* __restrict__ O) {
    const int h    = blockIdx.x;
    const int pair = blockIdx.y;
    const int tqA  = pair;
    const int tqB  = 31 - pair;
    const int b    = blockIdx.z;
    const int tid  = threadIdx.x;
    const int lane = tid & 63;
    const int w    = tid >> 6;
    const int m16  = lane & 15;
    const int quad = lane >> 4;
    const int q4   = quad * 4;

    __shared__ u16 Ks[2][64 * 64];
    __shared__ u16 Vs[2][64 * 64];
    __shared__ u16 PsA[64 * 64];
    __shared__ u16 PsB[64 * 64];

    const int srow0 = tid >> 3;
    const int skc0  = (tid & 7) * 8;
    const int sblk0 = ((skc0 >> 3) ^ (srow0 & 7)) << 3;
    const int srow1 = srow0 + 32;
    const int sblk1 = ((skc0 >> 3) ^ (srow1 & 7)) << 3;

    const size_t kbase = ((size_t)(b * S_)) * E_ + h * DH_;
    const size_t vbase = ((size_t)(b * 1024 + h * DH_)) * 2048;

    bf16x8 qfA[2], qfB[2];
    {
        const u16* qa = Qh + ((size_t)(b * S_ + tqA * 64 + w * 16 + m16)) * E_ + h * DH_;
        const u16* qb = Qh + ((size_t)(b * S_ + tqB * 64 + w * 16 + m16)) * E_ + h * DH_;
        qfA[0] = ld8(qa + quad * 8);  qfA[1] = ld8(qa + 32 + quad * 8);
        qfB[0] = ld8(qb + quad * 8);  qfB[1] = ld8(qb + 32 + quad * 8);
    }

    float lA[4] = {0.f, 0.f, 0.f, 0.f}, lB[4] = {0.f, 0.f, 0.f, 0.f};
    float4_ oA[4], oB[4];
#pragma unroll
    for (int dt = 0; dt < 4; dt++) { oA[dt] = (float4_){0.f,0.f,0.f,0.f}; oB[dt] = (float4_){0.f,0.f,0.f,0.f}; }

    *(bf16x8*)&Ks[0][srow0 * 64 + sblk0] = ld8(&Kh[kbase + (size_t)srow0 * E_ + skc0]);
    *(bf16x8*)&Ks[0][srow1 * 64 + sblk1] = ld8(&Kh[kbase + (size_t)srow1 * E_ + skc0]);
    *(bf16x8*)&Vs[0][srow0 * 64 + sblk0] = ld8(&Vt[vbase + (size_t)srow0 * 2048 + skc0]);
    *(bf16x8*)&Vs[0][srow1 * 64 + sblk1] = ld8(&Vt[vbase + (size_t)srow1 * 2048 + skc0]);
    __syncthreads();

    for (int t = 0; t <= tqB; t++) {
        const int cur = t & 1;

        bf16x8 kr0, kr1, vr0, vr1;
        const bool havepf = (t < tqB);
        if (havepf) {
            const size_t ko = kbase + (size_t)((t + 1) * 64) * E_;
            kr0 = ld8(&Kh[ko + (size_t)srow0 * E_ + skc0]);
            kr1 = ld8(&Kh[ko + (size_t)srow1 * E_ + skc0]);
            vr0 = ld8(&Vt[vbase + (size_t)srow0 * 2048 + (t + 1) * 64 + skc0]);
            vr1 = ld8(&Vt[vbase + (size_t)srow1 * 2048 + (t + 1) * 64 + skc0]);
        }

        auto process = [&](const bf16x8* qf, float* l_part, float4_* o_acc,
                           u16* Ps, int tqX) {
            const u16* Kc = &Ks[cur][0];
            const u16* Vc = &Vs[cur][0];
            float4_ sc[4];
#pragma unroll
            for (int ct = 0; ct < 4; ct++) sc[ct] = (float4_){0.f,0.f,0.f,0.f};
#pragma unroll
            for (int ks = 0; ks < 2; ks++)
#pragma unroll
                for (int ct = 0; ct < 4; ct++) {
                    bf16x8 kf = *(const bf16x8*)&Kc[sw64(ct * 16 + m16, ks * 32 + quad * 8)];
                    sc[ct] = __builtin_amdgcn_mfma_f32_16x16x32_bf16(qf[ks], kf, sc[ct], 0, 0, 0);
                }

            float p[4][4];
            if (t != tqX) {
#pragma unroll
                for (int ct = 0; ct < 4; ct++)
#pragma unroll
                    for (int r = 0; r < 4; r++) {
                        float pp = exp2f(sc[ct][r] * LOG2E_);
                        p[ct][r] = pp;
                        l_part[r] += pp;
                    }
            } else {
#pragma unroll
                for (int ct = 0; ct < 4; ct++)
#pragma unroll
                    for (int r = 0; r < 4; r++) {
                        int i_loc = w * 16 + q4 + r;
                        int j_loc = ct * 16 + m16;
                        bool allow = (j_loc < i_loc) || (tqX == 0 && i_loc == 0 && j_loc == 0);
                        float pp = allow ? exp2f(sc[ct][r] * LOG2E_) : 0.f;
                        p[ct][r] = pp;
                        l_part[r] += pp;
                    }
            }

#pragma unroll
            for (int ct = 0; ct < 4; ct++)
#pragma unroll
                for (int r = 0; r < 4; r++)
                    Ps[sw64(w * 16 + q4 + r, ct * 16 + m16)] = f2bf(p[ct][r]);

#pragma unroll
            for (int ks = 0; ks < 2; ks++) {
                bf16x8 pf = *(const bf16x8*)&Ps[sw64(w * 16 + m16, ks * 32 + quad * 8)];
#pragma unroll
                for (int dt = 0; dt < 4; dt++) {
                    bf16x8 vf = *(const bf16x8*)&Vc[sw64(dt * 16 + m16, ks * 32 + quad * 8)];
                    o_acc[dt] = __builtin_amdgcn_mfma_f32_16x16x32_bf16(pf, vf, o_acc[dt], 0, 0, 0);
                }
            }
        };

        process(qfB, lB, oB, PsB, tqB);
        if (t <= tqA) process(qfA, lA, oA, PsA, tqA);

        if (havepf) {
            const int nxt = cur ^ 1;
            *(bf16x8*)&Ks[nxt][srow0 * 64 + sblk0] = kr0;
            *(bf16x8*)&Ks[nxt][srow1 * 64 + sblk1] = kr1;
            *(bf16x8*)&Vs[nxt][srow0 * 64 + sblk0] = vr0;
            *(bf16x8*)&Vs[nxt][srow1 * 64 + sblk1] = vr1;
        }
        __syncthreads();
    }

    auto wrout = [&](const float4_* o_acc, const float* l_part, int tqX) {
        const size_t obase = ((size_t)(b * S_ + tqX * 64)) * E_ + h * DH_;
#pragma unroll
        for (int r = 0; r < 4; r++) {
            float l = l_part[r];
#pragma unroll
            for (int msk = 1; msk <= 8; msk <<= 1) l += __shfl_xor(l, msk);
            float inv_l = 1.0f / l;
            int row = w * 16 + q4 + r;
#pragma unroll
            for (int dt = 0; dt < 4; dt++) {
                int col = dt * 16 + m16;
                O[obase + (size_t)row * E_ + col] = f2bf(o_acc[dt][r] * inv_l);
            }
        }
    };
    wrout(oA, lA, tqA);
    wrout(oB, lB, tqB);
}

extern "C" void kernel_launch(void* const* d_in, const int* in_sizes, int n_in,
                              void* d_out, int out_size, void* d_ws, size_t ws_size,
                              hipStream_t stream) {
    const float* q  = (const float*)d_in[0];
    const float* k  = (const float*)d_in[1];
    const float* v  = (const float*)d_in[2];
    const float* Wq = (const float*)d_in[3];
    const float* Wk = (const float*)d_in[4];
    const float* Wv = (const float*)d_in[5];
    const float* Wo = (const float*)d_in[6];

    u16* ws  = (u16*)d_ws;
    u16* Qh  = ws;                          // [B*S,E] bf16, pre-scaled by SCALE_
    u16* Kh  = ws + (size_t)M_ * E_;
    u16* Vt  = ws + 2 * (size_t)M_ * E_;    // [B][1024][2048] bf16 V^T
    u16* AO  = ws + 3 * (size_t)M_ * E_;    // attn out; first 3*E*E aliased as W bufs
    u16* Wqb = AO;                          // dead before attn writes AO
    u16* Wkb = AO + (size_t)E_ * E_;
    u16* Wvb = AO + 2 * (size_t)E_ * E_;
    u16* Wob = ws + 4 * (size_t)M_ * E_;    // +2 MB

    dim3 blk(256);
    convw_kernel<<<dim3(512, 4), blk, 0, stream>>>(Wq, Wk, Wv, Wo, Wqb, Wkb, Wvb, Wob);
    proj_kernel<<<dim3(32, 8, 3), blk, 0, stream>>>(q, k, v, Wqb, Wkb, Wvb, Qh, Kh, Vt);
    attn_kernel<<<dim3(16, 16, 2), blk, 0, stream>>>(Qh, Kh, Vt, AO);
    out_kernel<<<dim3(32, 16), blk, 0, stream>>>(AO, Wob, (float*)d_out);
}